// Round 1
// baseline (2613.071 us; speedup 1.0000x reference)
//
#include <hip/hip_runtime.h>
#include <hip/hip_bf16.h>

#define CCH 256

__device__ __forceinline__ float lrelu(float v) { return v > 0.f ? v : 0.1f * v; }

// Direct 3x3 VALID conv, fused bias + leaky_relu(0.1).
// Input viewed as [B][CCH][HinRows][64] (row stride fixed 64).
// Block: 256 threads; thread r = tid>>3 (32 output rows), col group x0 = (tid&7)*8.
// Block tile: 32 rows x 64 cols x 4 output channels.
// Grid: (2 ytiles, 64 co-groups, B).
// DO_POOL=0: write out [B][CCH][Hout][64], zero-padding cols >= Wout.
// DO_POOL=1: no store; fused global-avg-pool -> atomicAdd into pool[B*CCH].
template<int DO_POOL>
__global__ __launch_bounds__(256)
void conv3x3_k(const float* __restrict__ in, const float* __restrict__ w,
               const float* __restrict__ bias, float* __restrict__ out,
               float* __restrict__ pool,
               int HinRows, int Hout, int Wout, float poolScale)
{
    __shared__ float tile[34 * 68];   // 34 input rows x 68 cols (17 float4, 16B-aligned rows)
    __shared__ float redbuf[4][4];

    const int tid = threadIdx.x;
    const int r   = tid >> 3;          // 0..31
    const int x0  = (tid & 7) * 8;     // 0,8,..,56
    const int y0  = blockIdx.x * 32;
    const int co0 = blockIdx.y * 4;
    const int b   = blockIdx.z;

    const float* inb = in + (size_t)b * CCH * HinRows * 64;

    float acc[4][8];
#pragma unroll
    for (int j = 0; j < 4; ++j) {
        float bv = bias[co0 + j];
#pragma unroll
        for (int p = 0; p < 8; ++p) acc[j][p] = bv;
    }

    for (int ci = 0; ci < CCH; ++ci) {
        const float* src = inb + (size_t)ci * HinRows * 64;
        // stage 34 x 68 floats (17 float4 per row); OOB rows / col-group 16 -> zeros
#pragma unroll
        for (int it = 0; it < 3; ++it) {
            int idx = tid + it * 256;
            if (idx < 34 * 17) {
                int rr = idx / 17, fx = idx - rr * 17;
                int gy = y0 + rr;
                float4 v = make_float4(0.f, 0.f, 0.f, 0.f);
                if (gy < HinRows && fx < 16)
                    v = *(const float4*)(src + (size_t)gy * 64 + fx * 4);
                *(float4*)&tile[idx * 4] = v;   // idx*4 == rr*68 + fx*4
            }
        }
        __syncthreads();

        const float* wp = w + ((size_t)co0 * CCH + ci) * 9;   // wave-uniform -> s_load
#pragma unroll
        for (int dy = 0; dy < 3; ++dy) {
            float rv[12];
            const float* tp = &tile[(r + dy) * 68 + x0];
            *(float4*)&rv[0] = *(const float4*)(tp);
            *(float4*)&rv[4] = *(const float4*)(tp + 4);
            *(float4*)&rv[8] = *(const float4*)(tp + 8);
#pragma unroll
            for (int j = 0; j < 4; ++j) {
                const float* wj = wp + (size_t)j * CCH * 9 + dy * 3;
                float w0 = wj[0], w1 = wj[1], w2 = wj[2];
#pragma unroll
                for (int p = 0; p < 8; ++p)
                    acc[j][p] += w0 * rv[p] + w1 * rv[p + 1] + w2 * rv[p + 2];
            }
        }
        __syncthreads();
    }

    const int y = y0 + r;
    if (DO_POOL) {
        float s[4];
#pragma unroll
        for (int j = 0; j < 4; ++j) {
            float sj = 0.f;
#pragma unroll
            for (int p = 0; p < 8; ++p) {
                int xx = x0 + p;
                if (y < Hout && xx < Wout) sj += lrelu(acc[j][p]);
            }
            s[j] = sj;
        }
#pragma unroll
        for (int j = 0; j < 4; ++j) {
            float v = s[j];
#pragma unroll
            for (int off = 32; off > 0; off >>= 1) v += __shfl_xor(v, off, 64);
            if ((tid & 63) == 0) redbuf[tid >> 6][j] = v;
        }
        __syncthreads();
        if (tid < 4) {
            float v = (redbuf[0][tid] + redbuf[1][tid]) + (redbuf[2][tid] + redbuf[3][tid]);
            atomicAdd(&pool[b * CCH + co0 + tid], v * poolScale);
        }
    } else {
        if (y < Hout) {
#pragma unroll
            for (int j = 0; j < 4; ++j) {
                float vals[8];
#pragma unroll
                for (int p = 0; p < 8; ++p) {
                    int xx = x0 + p;
                    vals[p] = (xx < Wout) ? lrelu(acc[j][p]) : 0.f;  // zero pad cols 62,63
                }
                float* op = out + ((size_t)(b * CCH + co0 + j) * Hout + y) * 64 + x0;
                *(float4*)op       = *(float4*)&vals[0];
                *(float4*)(op + 4) = *(float4*)&vals[4];
            }
        }
    }
}

__global__ __launch_bounds__(256)
void zero_pool_k(float* __restrict__ p)
{
    p[blockIdx.x * 256 + threadIdx.x] = 0.f;
}

// kern[b][o] = sum_c p[b][c] * w3[o][c] + b3[o];  o = c*9 + ky*3 + kx (row-major reshape)
__global__ __launch_bounds__(256)
void kern_gemm_k(const float* __restrict__ p, const float* __restrict__ w3,
                 const float* __restrict__ b3, float* __restrict__ kern)
{
    const int b = blockIdx.y;
    const int o = blockIdx.x * 256 + threadIdx.x;   // 0..2303
    __shared__ float pv[CCH];
    pv[threadIdx.x] = p[b * CCH + threadIdx.x];
    __syncthreads();
    float acc = b3[o];
    const float* wr = w3 + (size_t)o * CCH;
#pragma unroll 4
    for (int c = 0; c < CCH; c += 4) {
        float4 wv = *(const float4*)(wr + c);
        acc += wv.x * pv[c] + wv.y * pv[c + 1] + wv.z * pv[c + 2] + wv.w * pv[c + 3];
    }
    kern[(size_t)b * (9 * CCH) + o] = acc;
}

// Per-sample depthwise 3x3, SAME zero padding, + bias. One block per (b,c).
__global__ __launch_bounds__(256)
void dw_k(const float* __restrict__ x, const float* __restrict__ kern,
          const float* __restrict__ bias, float* __restrict__ out)
{
    const int bc = blockIdx.x;
    const int c = bc & (CCH - 1);
    const int b = bc >> 8;
    const float* kp = kern + (size_t)b * (9 * CCH) + c * 9;
    float k[9];
#pragma unroll
    for (int t = 0; t < 9; ++t) k[t] = kp[t];
    const float bs = bias[c];
    const float* xp = x + (size_t)bc * 4096;
    float* op = out + (size_t)bc * 4096;
#pragma unroll 2
    for (int it = 0; it < 16; ++it) {
        int px = it * 256 + (int)threadIdx.x;
        int yy = px >> 6, xx = px & 63;
        float a = bs;
#pragma unroll
        for (int dy = -1; dy <= 1; ++dy) {
            int sy = yy + dy;
            if (sy < 0 || sy > 63) continue;
#pragma unroll
            for (int dx = -1; dx <= 1; ++dx) {
                int sx = xx + dx;
                if (sx < 0 || sx > 63) continue;
                a += k[(dy + 1) * 3 + (dx + 1)] * xp[sy * 64 + sx];
            }
        }
        op[px] = a;
    }
}

extern "C" void kernel_launch(void* const* d_in, const int* in_sizes, int n_in,
                              void* d_out, int out_size, void* d_ws, size_t ws_size,
                              hipStream_t stream)
{
    const float* x    = (const float*)d_in[0];
    const float* kin  = (const float*)d_in[1];
    const float* w1   = (const float*)d_in[2];
    const float* b1   = (const float*)d_in[3];
    const float* w2   = (const float*)d_in[4];
    const float* b2   = (const float*)d_in[5];
    const float* w3   = (const float*)d_in[6];
    const float* b3   = (const float*)d_in[7];
    const float* bias = (const float*)d_in[8];

    const int B = 16;
    // ws layout: h1 [16][256][62][64] (65.0 MB) | pool [16*256] | kern [16*2304]
    float* h1   = (float*)d_ws;
    float* pool = h1 + (size_t)B * CCH * 62 * 64;
    float* kern = pool + B * CCH;

    float* out = (float*)d_out;

    hipLaunchKernelGGL(zero_pool_k, dim3(B), dim3(256), 0, stream, pool);
    hipLaunchKernelGGL((conv3x3_k<0>), dim3(2, 64, B), dim3(256), 0, stream,
                       kin, w1, b1, h1, (float*)nullptr, 64, 62, 62, 0.f);
    hipLaunchKernelGGL((conv3x3_k<1>), dim3(2, 64, B), dim3(256), 0, stream,
                       h1, w2, b2, (float*)nullptr, pool, 62, 60, 60, 1.f / 3600.f);
    hipLaunchKernelGGL(kern_gemm_k, dim3(9, B), dim3(256), 0, stream, pool, w3, b3, kern);
    hipLaunchKernelGGL(dw_k, dim3(B * CCH), dim3(256), 0, stream, x, kern, bias, out);
}

// Round 2
// 701.342 us; speedup vs baseline: 3.7258x; 3.7258x over previous
//
#include <hip/hip_runtime.h>
#include <hip/hip_bf16.h>
#include <stdint.h>

#define CCH 256

typedef __attribute__((ext_vector_type(8))) short short8;
typedef __attribute__((ext_vector_type(4))) float f32x4;

__device__ __forceinline__ float lrelu(float v) { return v > 0.f ? v : 0.1f * v; }

__device__ __forceinline__ unsigned short f2bf(float f) {
    __hip_bfloat16 h = __float2bfloat16(f);
    return *reinterpret_cast<unsigned short*>(&h);
}

// async global->LDS, 16B per lane; LDS dst must be wave-uniform (HW adds lane*16)
__device__ __forceinline__ void gl_lds16(const void* g, void* s) {
    __builtin_amdgcn_global_load_lds(
        (const __attribute__((address_space(1))) unsigned int*)(uintptr_t)g,
        (__attribute__((address_space(3))) unsigned int*)(unsigned int)(uintptr_t)s,
        16, 0, 0);
}

// NCHW fp32 -> NHWC bf16 for kin. grid (4 cg, 64 y, 16 b), block 256.
__global__ __launch_bounds__(256)
void nhwc_k(const float* __restrict__ in, unsigned short* __restrict__ out)
{
    __shared__ float t[64][65];
    const int tid = threadIdx.x;
    const int cg = blockIdx.x, y = blockIdx.y, b = blockIdx.z;
    const float* src = in + (((size_t)(b * 256 + cg * 64)) * 64 + y) * 64;
#pragma unroll
    for (int i = 0; i < 4; ++i) {
        int fidx = tid + i * 256;
        int cc = fidx >> 4, fx = fidx & 15;
        float4 v = *(const float4*)(src + (size_t)cc * 4096 + fx * 4);
        t[cc][fx * 4 + 0] = v.x; t[cc][fx * 4 + 1] = v.y;
        t[cc][fx * 4 + 2] = v.z; t[cc][fx * 4 + 3] = v.w;
    }
    __syncthreads();
    const int x = tid >> 2, cs = (tid & 3) * 16;
    union { unsigned short us[16]; uint4 v[2]; } u;
#pragma unroll
    for (int i = 0; i < 16; ++i) u.us[i] = f2bf(t[cs + i][x]);
    unsigned short* dst = out + (((size_t)(b * 64 + y) * 64 + x) * 256 + cg * 64 + cs);
    *(uint4*)dst = u.v[0];
    *((uint4*)dst + 1) = u.v[1];
}

// w[co][ci][9] fp32 -> wt[t][co][ci] bf16, both weights. grid (2304, 2), block 256.
__global__ __launch_bounds__(256)
void wtr_k(const float* __restrict__ w1, const float* __restrict__ w2,
           unsigned short* __restrict__ o1, unsigned short* __restrict__ o2)
{
    const int ci = threadIdx.x;
    const int t  = blockIdx.x >> 8;
    const int co = blockIdx.x & 255;
    const float* w = blockIdx.y ? w2 : w1;
    unsigned short* o = blockIdx.y ? o2 : o1;
    o[((size_t)t * 256 + co) * 256 + ci] = f2bf(w[((size_t)co * 256 + ci) * 9 + t]);
}

__global__ __launch_bounds__(256)
void zero_pool_k(float* __restrict__ p) { p[blockIdx.x * 256 + threadIdx.x] = 0.f; }

// Implicit-GEMM 3x3 VALID conv, bf16 MFMA 16x16x32.
// M=Cout (block 128), N=pixels (block 128, per-image padded), K = 9 taps * 256 ci.
// im: NHWC bf16 [b][Win][Win][256]; wt: [9][256][256] bf16.
// POOL=0: h1 NHWC bf16 out (bias+lrelu). POOL=1: bias+lrelu+sum -> atomicAdd pool.
// grid (2 mtiles, ceil(Wout^2/128), 16 b), block 256.
template<int POOL>
__global__ __launch_bounds__(256)
void convmm_k(const unsigned short* __restrict__ im, const unsigned short* __restrict__ wt,
              const float* __restrict__ bias, unsigned short* __restrict__ outp,
              float* __restrict__ pool, int Win, int Wout)
{
    // 4 k-chunk planes of [128 rows][8 elems], plane stride 1032 elems (2064B:
    // +16B pad breaks pow-2 bank aliasing; wave-call contiguity preserved).
    __shared__ __align__(16) short As[2 * 4 * 1032];
    short* Bs = As + 4 * 1032;

    const int tid  = threadIdx.x;
    const int wave = tid >> 6;
    const int lane = tid & 63;
    const int quad = lane >> 4;
    const int l15  = lane & 15;
    const int wm   = (wave & 1) * 64;
    const int wn   = (wave >> 1) * 64;
    const int cb0  = blockIdx.x * 128;
    const int nb0  = blockIdx.y * 128;
    const int b    = blockIdx.z;
    const int Nval = Wout * Wout;

    // staging: wave stages plane q=wave; call h covers rows h*64+lane (16B/row)
    const unsigned short* arow[2];
    size_t pb[2];
#pragma unroll
    for (int h = 0; h < 2; ++h) {
        int m = h * 64 + lane;
        arow[h] = wt + ((size_t)(cb0 + m)) * 256 + wave * 8;
        int nn = nb0 + m; if (nn > Nval - 1) nn = Nval - 1;   // clamp padded px
        int y = nn / Wout, x = nn - y * Wout;
        pb[h] = ((size_t)b * Win * Win + (size_t)y * Win + x) * 256 + wave * 8;
    }
    short* aldst[2]; short* bldst[2];
#pragma unroll
    for (int h = 0; h < 2; ++h) {
        aldst[h] = As + wave * 1032 + h * 512;
        bldst[h] = Bs + wave * 1032 + h * 512;
    }

    f32x4 acc[4][4];
#pragma unroll
    for (int i = 0; i < 4; ++i)
#pragma unroll
        for (int j = 0; j < 4; ++j) { f32x4 z = {0.f, 0.f, 0.f, 0.f}; acc[i][j] = z; }

    for (int t = 0; t < 9; ++t) {
        const int ky = t / 3, kx = t - ky * 3;
        const size_t tapoff = (size_t)(ky * Win + kx) * 256;
        const size_t awoff  = (size_t)t * 65536;           // t*256*256
        for (int kc = 0; kc < 8; ++kc) {
            const int koff = kc * 32;
#pragma unroll
            for (int h = 0; h < 2; ++h) {
                gl_lds16(arow[h] + awoff + koff, aldst[h]);
                gl_lds16(im + pb[h] + tapoff + koff, bldst[h]);
            }
            __syncthreads();
            short8 a[4], bf[4];
#pragma unroll
            for (int i = 0; i < 4; ++i)
                a[i]  = *(const short8*)(As + quad * 1032 + (wm + i * 16 + l15) * 8);
#pragma unroll
            for (int j = 0; j < 4; ++j)
                bf[j] = *(const short8*)(Bs + quad * 1032 + (wn + j * 16 + l15) * 8);
#pragma unroll
            for (int i = 0; i < 4; ++i)
#pragma unroll
                for (int j = 0; j < 4; ++j)
                    acc[i][j] = __builtin_amdgcn_mfma_f32_16x16x32_bf16(a[i], bf[j], acc[i][j], 0, 0, 0);
            __syncthreads();
        }
    }

    // D layout: col(px)=l15, row(co)=quad*4+reg
    const int co_l = cb0 + wm + quad * 4;
    if (!POOL) {
#pragma unroll
        for (int i = 0; i < 4; ++i) {
            float4 bv = *(const float4*)(bias + co_l + i * 16);
#pragma unroll
            for (int j = 0; j < 4; ++j) {
                int nn = nb0 + wn + j * 16 + l15;
                if (nn < Nval) {
                    ushort4 pk = make_ushort4(
                        f2bf(lrelu(acc[i][j].x + bv.x)),
                        f2bf(lrelu(acc[i][j].y + bv.y)),
                        f2bf(lrelu(acc[i][j].z + bv.z)),
                        f2bf(lrelu(acc[i][j].w + bv.w)));
                    unsigned short* dst = outp + ((size_t)b * Nval + nn) * 256 + co_l + i * 16;
                    *(ushort4*)dst = pk;
                }
            }
        }
    } else {
#pragma unroll
        for (int i = 0; i < 4; ++i) {
            float4 bv = *(const float4*)(bias + co_l + i * 16);
            float s0 = 0.f, s1 = 0.f, s2 = 0.f, s3 = 0.f;
#pragma unroll
            for (int j = 0; j < 4; ++j) {
                int nn = nb0 + wn + j * 16 + l15;
                if (nn < Nval) {
                    s0 += lrelu(acc[i][j].x + bv.x);
                    s1 += lrelu(acc[i][j].y + bv.y);
                    s2 += lrelu(acc[i][j].z + bv.z);
                    s3 += lrelu(acc[i][j].w + bv.w);
                }
            }
#pragma unroll
            for (int off = 1; off < 16; off <<= 1) {
                s0 += __shfl_xor(s0, off, 64);
                s1 += __shfl_xor(s1, off, 64);
                s2 += __shfl_xor(s2, off, 64);
                s3 += __shfl_xor(s3, off, 64);
            }
            if (l15 == 0) {
                float* pp = pool + b * 256 + co_l + i * 16;
                atomicAdd(pp + 0, s0); atomicAdd(pp + 1, s1);
                atomicAdd(pp + 2, s2); atomicAdd(pp + 3, s3);
            }
        }
    }
}

// kern[b][o] = (1/3600) * sum_c pool[b][c]*w3[o][c] + b3[o]
__global__ __launch_bounds__(256)
void kern_gemm_k(const float* __restrict__ p, const float* __restrict__ w3,
                 const float* __restrict__ b3, float* __restrict__ kern)
{
    const int b = blockIdx.y;
    const int o = blockIdx.x * 256 + threadIdx.x;
    __shared__ float pv[CCH];
    pv[threadIdx.x] = p[b * CCH + threadIdx.x] * (1.f / 3600.f);
    __syncthreads();
    float acc = b3[o];
    const float* wr = w3 + (size_t)o * CCH;
#pragma unroll 4
    for (int c = 0; c < CCH; c += 4) {
        float4 wv = *(const float4*)(wr + c);
        acc += wv.x * pv[c] + wv.y * pv[c + 1] + wv.z * pv[c + 2] + wv.w * pv[c + 3];
    }
    kern[(size_t)b * (9 * CCH) + o] = acc;
}

// Per-sample depthwise 3x3 SAME + bias, fp32. One block per (b,c).
__global__ __launch_bounds__(256)
void dw_k(const float* __restrict__ x, const float* __restrict__ kern,
          const float* __restrict__ bias, float* __restrict__ out)
{
    const int bc = blockIdx.x;
    const int c = bc & (CCH - 1);
    const int b = bc >> 8;
    const float* kp = kern + (size_t)b * (9 * CCH) + c * 9;
    float k[9];
#pragma unroll
    for (int t = 0; t < 9; ++t) k[t] = kp[t];
    const float bs = bias[c];
    const float* xp = x + (size_t)bc * 4096;
    float* op = out + (size_t)bc * 4096;
#pragma unroll 2
    for (int it = 0; it < 16; ++it) {
        int px = it * 256 + (int)threadIdx.x;
        int yy = px >> 6, xx = px & 63;
        float a = bs;
#pragma unroll
        for (int dy = -1; dy <= 1; ++dy) {
            int sy = yy + dy;
            if (sy < 0 || sy > 63) continue;
#pragma unroll
            for (int dx = -1; dx <= 1; ++dx) {
                int sx = xx + dx;
                if (sx < 0 || sx > 63) continue;
                a += k[(dy + 1) * 3 + (dx + 1)] * xp[sy * 64 + sx];
            }
        }
        op[px] = a;
    }
}

extern "C" void kernel_launch(void* const* d_in, const int* in_sizes, int n_in,
                              void* d_out, int out_size, void* d_ws, size_t ws_size,
                              hipStream_t stream)
{
    const float* x    = (const float*)d_in[0];
    const float* kin  = (const float*)d_in[1];
    const float* w1   = (const float*)d_in[2];
    const float* b1   = (const float*)d_in[3];
    const float* w2   = (const float*)d_in[4];
    const float* b2   = (const float*)d_in[5];
    const float* w3   = (const float*)d_in[6];
    const float* b3   = (const float*)d_in[7];
    const float* bias = (const float*)d_in[8];

    // ws: imA bf16 [16][64][64][256] | h1 bf16 [16][3844][256] | w1t | w2t | pool | kern
    unsigned short* imA = (unsigned short*)d_ws;
    unsigned short* h1  = imA + (size_t)16 * 4096 * 256;
    unsigned short* w1t = h1 + (size_t)16 * 3844 * 256;
    unsigned short* w2t = w1t + (size_t)9 * 256 * 256;
    float* pool = (float*)(w2t + (size_t)9 * 256 * 256);
    float* kern = pool + 16 * 256;

    float* out = (float*)d_out;

    hipLaunchKernelGGL(zero_pool_k, dim3(16), dim3(256), 0, stream, pool);
    hipLaunchKernelGGL(nhwc_k, dim3(4, 64, 16), dim3(256), 0, stream, kin, imA);
    hipLaunchKernelGGL(wtr_k, dim3(2304, 2), dim3(256), 0, stream, w1, w2, w1t, w2t);
    hipLaunchKernelGGL((convmm_k<0>), dim3(2, 31, 16), dim3(256), 0, stream,
                       imA, w1t, b1, h1, (float*)nullptr, 64, 62);
    hipLaunchKernelGGL((convmm_k<1>), dim3(2, 29, 16), dim3(256), 0, stream,
                       h1, w2t, b2, (unsigned short*)nullptr, pool, 62, 60);
    hipLaunchKernelGGL(kern_gemm_k, dim3(9, 16), dim3(256), 0, stream, pool, w3, b3, kern);
    hipLaunchKernelGGL(dw_k, dim3(16 * 256), dim3(256), 0, stream, x, kern, bias, out);
}

// Round 3
// 505.446 us; speedup vs baseline: 5.1698x; 1.3876x over previous
//
#include <hip/hip_runtime.h>
#include <hip/hip_bf16.h>
#include <stdint.h>

#define CCH 256

typedef __attribute__((ext_vector_type(8))) short short8;
typedef __attribute__((ext_vector_type(4))) float f32x4;

__device__ __forceinline__ float lrelu(float v) { return v > 0.f ? v : 0.1f * v; }

__device__ __forceinline__ unsigned short f2bf(float f) {
    __hip_bfloat16 h = __float2bfloat16(f);
    return *reinterpret_cast<unsigned short*>(&h);
}

// async global->LDS, 16B per lane; LDS dst is wave-uniform base (HW adds lane*16)
__device__ __forceinline__ void gl_lds16(const void* g, void* s) {
    __builtin_amdgcn_global_load_lds(
        (const __attribute__((address_space(1))) unsigned int*)(uintptr_t)g,
        (__attribute__((address_space(3))) unsigned int*)(unsigned int)(uintptr_t)s,
        16, 0, 0);
}

// NCHW fp32 -> channel-chunked bf16: out[b][kc][y*64+x][32ci].
// grid (8 kc, 64 y, 16 b), block 256.
__global__ __launch_bounds__(256)
void nhwc_k(const float* __restrict__ in, unsigned short* __restrict__ out)
{
    __shared__ float t[32][65];
    const int tid = threadIdx.x;
    const int kc = blockIdx.x, y = blockIdx.y, b = blockIdx.z;
    const float* src = in + ((size_t)(b * 256 + kc * 32)) * 4096 + y * 64;
#pragma unroll
    for (int i = 0; i < 2; ++i) {
        int idx = tid + i * 256;            // 0..511
        int cl = idx >> 4, xg = idx & 15;
        float4 v = *(const float4*)(src + (size_t)cl * 4096 + xg * 4);
        t[cl][xg * 4 + 0] = v.x; t[cl][xg * 4 + 1] = v.y;
        t[cl][xg * 4 + 2] = v.z; t[cl][xg * 4 + 3] = v.w;
    }
    __syncthreads();
    const int x = tid >> 2, cg = tid & 3;
    union { unsigned short us[8]; uint4 v; } u;
#pragma unroll
    for (int j = 0; j < 8; ++j) u.us[j] = f2bf(t[cg * 8 + j][x]);
    unsigned short* dst = out + (((size_t)(b * 8 + kc) * 4096 + y * 64 + x) * 32 + cg * 8);
    *(uint4*)dst = u.v;
}

// w[co][ci][9] fp32 -> wt[kc][t][q][co][8] bf16 (ci = kc*32 + q*8 + u).
// grid (72, 2), block 256 (= co).
__global__ __launch_bounds__(256)
void wtr_k(const float* __restrict__ w1, const float* __restrict__ w2,
           unsigned short* __restrict__ o1, unsigned short* __restrict__ o2)
{
    const int kc = blockIdx.x / 9, t = blockIdx.x - kc * 9;
    const float* w = blockIdx.y ? w2 : w1;
    unsigned short* o = blockIdx.y ? o2 : o1;
    const int co = threadIdx.x;
#pragma unroll
    for (int q = 0; q < 4; ++q) {
        union { unsigned short us[8]; uint4 v; } u;
#pragma unroll
        for (int uu = 0; uu < 8; ++uu)
            u.us[uu] = f2bf(w[((size_t)co * 256 + kc * 32 + q * 8 + uu) * 9 + t]);
        *(uint4*)(o + ((size_t)((kc * 9 + t) * 4 + q)) * 2048 + co * 8) = u.v;
    }
}

__global__ __launch_bounds__(256)
void zero_pool_k(float* __restrict__ p) { p[blockIdx.x * 256 + threadIdx.x] = 0.f; }

// Implicit-GEMM 3x3 VALID conv, bf16 MFMA 16x16x32.
// M=Cout (block 128), N=pixels (block 128), K = 8 ci-chunks(outer) x 9 taps(inner) x 32.
// im: [b][kc][WIN*WIN][32] bf16; wt: [kc][t][q][co][8] bf16.
// POOL=0: h1 out [b][kc'][NVAL][32] (bias+lrelu, bf16). POOL=1: sum -> atomicAdd pool.
// grid (2 mtiles, ceil(NVAL/128), 16 b), block 256.
template<int POOL, int WIN, int WOUT>
__global__ __launch_bounds__(256)
void convmm_k(const unsigned short* __restrict__ im, const unsigned short* __restrict__ wt,
              const float* __restrict__ bias, unsigned short* __restrict__ outp,
              float* __restrict__ pool)
{
    constexpr int HINPIX = WIN * WIN;
    constexpr int NVAL   = WOUT * WOUT;
    // 4 ci8 planes of [128 rows][8 elems], plane stride 1032 shorts (+16B pad).
    __shared__ __align__(16) short As[2 * 4 * 1032];
    short* Bs = As + 4 * 1032;
    __shared__ float redbuf[4][4];

    const int tid  = threadIdx.x;
    const int wave = tid >> 6;
    const int lane = tid & 63;
    const int quad = lane >> 4;
    const int l15  = lane & 15;
    const int wm   = (wave & 1) * 64;
    const int wn   = (wave >> 1) * 64;
    const int cb0  = blockIdx.x * 128;
    const int nb0  = blockIdx.y * 128;
    const int b    = blockIdx.z;

    // per-call (h) staging bases: lanes cover rows m = h*64 + lane
    const unsigned short* abase[2];
    size_t bofs[2];
#pragma unroll
    for (int h = 0; h < 2; ++h) {
        int m = h * 64 + lane;
        abase[h] = wt + (size_t)(cb0 + m) * 8 + wave * 2048;
        int nn = nb0 + m; if (nn > NVAL - 1) nn = NVAL - 1;
        int y = nn / WOUT, x = nn - y * WOUT;
        bofs[h] = ((size_t)(b * 8) * HINPIX + (size_t)y * WIN + x) * 32 + wave * 8;
    }
    short* aldst[2]; short* bldst[2];
#pragma unroll
    for (int h = 0; h < 2; ++h) {
        aldst[h] = As + wave * 1032 + h * 512;
        bldst[h] = Bs + wave * 1032 + h * 512;
    }

    f32x4 acc[4][4];
#pragma unroll
    for (int i = 0; i < 4; ++i)
#pragma unroll
        for (int j = 0; j < 4; ++j) { f32x4 z = {0.f, 0.f, 0.f, 0.f}; acc[i][j] = z; }

    for (int kc = 0; kc < 8; ++kc) {
#pragma unroll
        for (int t = 0; t < 9; ++t) {
            const int ky = t / 3, kx = t - ky * 3;
            const size_t aoff = (size_t)(kc * 9 + t) * 8192;
            const size_t boff = ((size_t)kc * HINPIX + ky * WIN + kx) * 32;
#pragma unroll
            for (int h = 0; h < 2; ++h) {
                gl_lds16(abase[h] + aoff, aldst[h]);
                gl_lds16(im + bofs[h] + boff, bldst[h]);
            }
            __syncthreads();
            short8 a[4], bf[4];
#pragma unroll
            for (int i = 0; i < 4; ++i)
                a[i]  = *(const short8*)(As + quad * 1032 + (wm + i * 16 + l15) * 8);
#pragma unroll
            for (int j = 0; j < 4; ++j)
                bf[j] = *(const short8*)(Bs + quad * 1032 + (wn + j * 16 + l15) * 8);
#pragma unroll
            for (int i = 0; i < 4; ++i)
#pragma unroll
                for (int j = 0; j < 4; ++j)
                    acc[i][j] = __builtin_amdgcn_mfma_f32_16x16x32_bf16(a[i], bf[j], acc[i][j], 0, 0, 0);
            __syncthreads();
        }
    }

    // D layout: col(px)=l15, row(co)=quad*4+reg
    const int co_l = cb0 + wm + quad * 4;
    if (!POOL) {
#pragma unroll
        for (int i = 0; i < 4; ++i) {
            float4 bv = *(const float4*)(bias + co_l + i * 16);
            const int c0 = co_l + i * 16;
            unsigned short* dstp = outp + ((size_t)(b * 8 + (c0 >> 5)) * NVAL) * 32 + (c0 & 31);
#pragma unroll
            for (int j = 0; j < 4; ++j) {
                int nn = nb0 + wn + j * 16 + l15;
                if (nn < NVAL) {
                    ushort4 pk = make_ushort4(
                        f2bf(lrelu(acc[i][j].x + bv.x)),
                        f2bf(lrelu(acc[i][j].y + bv.y)),
                        f2bf(lrelu(acc[i][j].z + bv.z)),
                        f2bf(lrelu(acc[i][j].w + bv.w)));
                    *(ushort4*)(dstp + (size_t)nn * 32) = pk;
                }
            }
        }
    } else {
#pragma unroll
        for (int i = 0; i < 4; ++i) {
            float4 bv = *(const float4*)(bias + co_l + i * 16);
            float s0 = 0.f, s1 = 0.f, s2 = 0.f, s3 = 0.f;
#pragma unroll
            for (int j = 0; j < 4; ++j) {
                int nn = nb0 + wn + j * 16 + l15;
                if (nn < NVAL) {
                    s0 += lrelu(acc[i][j].x + bv.x);
                    s1 += lrelu(acc[i][j].y + bv.y);
                    s2 += lrelu(acc[i][j].z + bv.z);
                    s3 += lrelu(acc[i][j].w + bv.w);
                }
            }
#pragma unroll
            for (int off = 1; off < 16; off <<= 1) {
                s0 += __shfl_xor(s0, off, 64);
                s1 += __shfl_xor(s1, off, 64);
                s2 += __shfl_xor(s2, off, 64);
                s3 += __shfl_xor(s3, off, 64);
            }
            if (l15 == 0) {
                float* pp = pool + b * 256 + co_l + i * 16;
                atomicAdd(pp + 0, s0); atomicAdd(pp + 1, s1);
                atomicAdd(pp + 2, s2); atomicAdd(pp + 3, s3);
            }
        }
    }
}

// kern[b][o] = (1/3600) * sum_c pool[b][c]*w3[o][c] + b3[o]
__global__ __launch_bounds__(256)
void kern_gemm_k(const float* __restrict__ p, const float* __restrict__ w3,
                 const float* __restrict__ b3, float* __restrict__ kern)
{
    const int b = blockIdx.y;
    const int o = blockIdx.x * 256 + threadIdx.x;
    __shared__ float pv[CCH];
    pv[threadIdx.x] = p[b * CCH + threadIdx.x] * (1.f / 3600.f);
    __syncthreads();
    float acc = b3[o];
    const float* wr = w3 + (size_t)o * CCH;
#pragma unroll 4
    for (int c = 0; c < CCH; c += 4) {
        float4 wv = *(const float4*)(wr + c);
        acc += wv.x * pv[c] + wv.y * pv[c + 1] + wv.z * pv[c + 2] + wv.w * pv[c + 3];
    }
    kern[(size_t)b * (9 * CCH) + o] = acc;
}

// Per-sample depthwise 3x3 SAME + bias, fp32. One block per (b,c).
__global__ __launch_bounds__(256)
void dw_k(const float* __restrict__ x, const float* __restrict__ kern,
          const float* __restrict__ bias, float* __restrict__ out)
{
    const int bc = blockIdx.x;
    const int c = bc & (CCH - 1);
    const int b = bc >> 8;
    const float* kp = kern + (size_t)b * (9 * CCH) + c * 9;
    float k[9];
#pragma unroll
    for (int t = 0; t < 9; ++t) k[t] = kp[t];
    const float bs = bias[c];
    const float* xp = x + (size_t)bc * 4096;
    float* op = out + (size_t)bc * 4096;
#pragma unroll 2
    for (int it = 0; it < 16; ++it) {
        int px = it * 256 + (int)threadIdx.x;
        int yy = px >> 6, xx = px & 63;
        float a = bs;
#pragma unroll
        for (int dy = -1; dy <= 1; ++dy) {
            int sy = yy + dy;
            if (sy < 0 || sy > 63) continue;
#pragma unroll
            for (int dx = -1; dx <= 1; ++dx) {
                int sx = xx + dx;
                if (sx < 0 || sx > 63) continue;
                a += k[(dy + 1) * 3 + (dx + 1)] * xp[sy * 64 + sx];
            }
        }
        op[px] = a;
    }
}

extern "C" void kernel_launch(void* const* d_in, const int* in_sizes, int n_in,
                              void* d_out, int out_size, void* d_ws, size_t ws_size,
                              hipStream_t stream)
{
    const float* x    = (const float*)d_in[0];
    const float* kin  = (const float*)d_in[1];
    const float* w1   = (const float*)d_in[2];
    const float* b1   = (const float*)d_in[3];
    const float* w2   = (const float*)d_in[4];
    const float* b2   = (const float*)d_in[5];
    const float* w3   = (const float*)d_in[6];
    const float* b3   = (const float*)d_in[7];
    const float* bias = (const float*)d_in[8];

    // ws: imA [16][8][4096][32] bf16 | h1 [16][8][3844][32] bf16 (+slack) | w1t | w2t | pool | kern
    unsigned short* imA = (unsigned short*)d_ws;
    unsigned short* h1  = imA + (size_t)16 * 8 * 4096 * 32;
    unsigned short* w1t = h1 + (size_t)16 * 8 * 3844 * 32 + 8192;   // slack for clamped-tap reads
    unsigned short* w2t = w1t + (size_t)72 * 4 * 2048;
    float* pool = (float*)(w2t + (size_t)72 * 4 * 2048);
    float* kern = pool + 16 * 256;

    float* out = (float*)d_out;

    hipLaunchKernelGGL(zero_pool_k, dim3(16), dim3(256), 0, stream, pool);
    hipLaunchKernelGGL(nhwc_k, dim3(8, 64, 16), dim3(256), 0, stream, kin, imA);
    hipLaunchKernelGGL(wtr_k, dim3(72, 2), dim3(256), 0, stream, w1, w2, w1t, w2t);
    hipLaunchKernelGGL((convmm_k<0, 64, 62>), dim3(2, 31, 16), dim3(256), 0, stream,
                       imA, w1t, b1, h1, (float*)nullptr);
    hipLaunchKernelGGL((convmm_k<1, 62, 60>), dim3(2, 29, 16), dim3(256), 0, stream,
                       h1, w2t, b2, (unsigned short*)nullptr, pool);
    hipLaunchKernelGGL(kern_gemm_k, dim3(9, 16), dim3(256), 0, stream, pool, w3, b3, kern);
    hipLaunchKernelGGL(dw_k, dim3(16 * 256), dim3(256), 0, stream, x, kern, bias, out);
}

// Round 4
// 436.936 us; speedup vs baseline: 5.9804x; 1.1568x over previous
//
#include <hip/hip_runtime.h>
#include <hip/hip_bf16.h>
#include <stdint.h>

#define CCH 256

typedef __attribute__((ext_vector_type(8))) short short8;
typedef __attribute__((ext_vector_type(4))) float f32x4;

__device__ __forceinline__ float lrelu(float v) { return v > 0.f ? v : 0.1f * v; }

__device__ __forceinline__ unsigned short f2bf(float f) {
    __hip_bfloat16 h = __float2bfloat16(f);
    return *reinterpret_cast<unsigned short*>(&h);
}

// async global->LDS, 16B per lane; LDS dst is wave-uniform base (HW adds lane*16)
__device__ __forceinline__ void gl_lds16(const void* g, void* s) {
    __builtin_amdgcn_global_load_lds(
        (const __attribute__((address_space(1))) unsigned int*)(uintptr_t)g,
        (__attribute__((address_space(3))) unsigned int*)(unsigned int)(uintptr_t)s,
        16, 0, 0);
}

// NCHW fp32 -> channel-chunked bf16: out[b][kc][y*64+x][32ci].
// grid (8 kc, 64 y, 16 b), block 256.
__global__ __launch_bounds__(256)
void nhwc_k(const float* __restrict__ in, unsigned short* __restrict__ out)
{
    __shared__ float t[32][65];
    const int tid = threadIdx.x;
    const int kc = blockIdx.x, y = blockIdx.y, b = blockIdx.z;
    const float* src = in + ((size_t)(b * 256 + kc * 32)) * 4096 + y * 64;
#pragma unroll
    for (int i = 0; i < 2; ++i) {
        int idx = tid + i * 256;            // 0..511
        int cl = idx >> 4, xg = idx & 15;
        float4 v = *(const float4*)(src + (size_t)cl * 4096 + xg * 4);
        t[cl][xg * 4 + 0] = v.x; t[cl][xg * 4 + 1] = v.y;
        t[cl][xg * 4 + 2] = v.z; t[cl][xg * 4 + 3] = v.w;
    }
    __syncthreads();
    const int x = tid >> 2, cg = tid & 3;
    union { unsigned short us[8]; uint4 v; } u;
#pragma unroll
    for (int j = 0; j < 8; ++j) u.us[j] = f2bf(t[cg * 8 + j][x]);
    unsigned short* dst = out + (((size_t)(b * 8 + kc) * 4096 + y * 64 + x) * 32 + cg * 8);
    *(uint4*)dst = u.v;
}

// w[co][ci][9] fp32 -> wt[kc][t][q][co][8] bf16 (ci = kc*32 + q*8 + u).
// grid (72, 2), block 256 (= co).
__global__ __launch_bounds__(256)
void wtr_k(const float* __restrict__ w1, const float* __restrict__ w2,
           unsigned short* __restrict__ o1, unsigned short* __restrict__ o2)
{
    const int kc = blockIdx.x / 9, t = blockIdx.x - kc * 9;
    const float* w = blockIdx.y ? w2 : w1;
    unsigned short* o = blockIdx.y ? o2 : o1;
    const int co = threadIdx.x;
#pragma unroll
    for (int q = 0; q < 4; ++q) {
        union { unsigned short us[8]; uint4 v; } u;
#pragma unroll
        for (int uu = 0; uu < 8; ++uu)
            u.us[uu] = f2bf(w[((size_t)co * 256 + kc * 32 + q * 8 + uu) * 9 + t]);
        *(uint4*)(o + ((size_t)((kc * 9 + t) * 4 + q)) * 2048 + co * 8) = u.v;
    }
}

__global__ __launch_bounds__(256)
void zero_pool_k(float* __restrict__ p) { p[blockIdx.x * 256 + threadIdx.x] = 0.f; }

// Implicit-GEMM 3x3 VALID conv, bf16 MFMA 16x16x32.
// M=Cout (block 128), N=pixels (block 128), K = 72 stages (kc,tap) x 32, 2 stages/barrier.
// im: [b][kc][WIN*WIN][32] bf16; wt: [kc][t][q][co][8] bf16.
// POOL=0: h1 out [b][kc'][NVAL][32] (bias+lrelu, bf16). POOL=1: sum -> atomicAdd pool.
// grid (2 mtiles, ceil(NVAL/128), 16 b), block 256.
template<int POOL, int WIN, int WOUT>
__global__ __launch_bounds__(256)
void convmm_k(const unsigned short* __restrict__ im, const unsigned short* __restrict__ wt,
              const float* __restrict__ bias, unsigned short* __restrict__ outp,
              float* __restrict__ pool)
{
    constexpr int HINPIX = WIN * WIN;
    constexpr int NVAL   = WOUT * WOUT;
    // 16 planes of [128 rows][8 shorts], stride 1032 shorts (+16B pad).
    // plane((u,mat,q)) at ((u*2+mat)*4+q)*1032.  u=stage-in-pair, mat: 0=A 1=B.
    __shared__ __align__(16) short Ls[16 * 1032];

    const int tid  = threadIdx.x;
    const int wave = tid >> 6;
    const int lane = tid & 63;
    const int quad = lane >> 4;
    const int l15  = lane & 15;
    const int wm   = (wave & 1) * 64;
    const int wn   = (wave >> 1) * 64;
    const int cb0  = blockIdx.x * 128;
    const int nb0  = blockIdx.y * 128;
    const int b    = blockIdx.z;

    // per-call (h) staging bases: lanes cover rows m = h*64 + lane
    const unsigned short* abase[2];
    size_t bofs[2];
#pragma unroll
    for (int h = 0; h < 2; ++h) {
        int m = h * 64 + lane;
        abase[h] = wt + (size_t)(cb0 + m) * 8 + wave * 2048;
        int nn = nb0 + m; if (nn > NVAL - 1) nn = NVAL - 1;
        int y = nn / WOUT, x = nn - y * WOUT;
        bofs[h] = ((size_t)(b * 8) * HINPIX + (size_t)y * WIN + x) * 32 + wave * 8;
    }

    f32x4 acc[4][4];
#pragma unroll
    for (int i = 0; i < 4; ++i)
#pragma unroll
        for (int j = 0; j < 4; ++j) { f32x4 z = {0.f, 0.f, 0.f, 0.f}; acc[i][j] = z; }

    for (int s = 0; s < 72; s += 2) {
#pragma unroll
        for (int u = 0; u < 2; ++u) {
            const int ss = s + u;
            const int kc = ss / 9, t = ss - kc * 9;
            const int ky = t / 3, kx = t - ky * 3;
            const size_t aoff = (size_t)ss * 8192;
            const size_t boff = ((size_t)kc * HINPIX + ky * WIN + kx) * 32;
            short* al = Ls + ((u * 2 + 0) * 4 + wave) * 1032;
            short* bl = Ls + ((u * 2 + 1) * 4 + wave) * 1032;
#pragma unroll
            for (int h = 0; h < 2; ++h) {
                gl_lds16(abase[h] + aoff, al + h * 512);
                gl_lds16(im + bofs[h] + boff, bl + h * 512);
            }
        }
        __syncthreads();
#pragma unroll
        for (int u = 0; u < 2; ++u) {
            const short* ap = Ls + ((u * 2 + 0) * 4 + quad) * 1032;
            const short* bp = Ls + ((u * 2 + 1) * 4 + quad) * 1032;
            short8 a[4], bf[4];
#pragma unroll
            for (int i = 0; i < 4; ++i)
                a[i]  = *(const short8*)(ap + (wm + i * 16 + l15) * 8);
#pragma unroll
            for (int j = 0; j < 4; ++j)
                bf[j] = *(const short8*)(bp + (wn + j * 16 + l15) * 8);
#pragma unroll
            for (int i = 0; i < 4; ++i)
#pragma unroll
                for (int j = 0; j < 4; ++j)
                    acc[i][j] = __builtin_amdgcn_mfma_f32_16x16x32_bf16(a[i], bf[j], acc[i][j], 0, 0, 0);
        }
        __syncthreads();
    }

    // D layout: col(px)=l15, row(co)=quad*4+reg
    const int co_l = cb0 + wm + quad * 4;
    if (!POOL) {
#pragma unroll
        for (int i = 0; i < 4; ++i) {
            float4 bv = *(const float4*)(bias + co_l + i * 16);
            const int c0 = co_l + i * 16;
            unsigned short* dstp = outp + ((size_t)(b * 8 + (c0 >> 5)) * NVAL) * 32 + (c0 & 31);
#pragma unroll
            for (int j = 0; j < 4; ++j) {
                int nn = nb0 + wn + j * 16 + l15;
                if (nn < NVAL) {
                    ushort4 pk = make_ushort4(
                        f2bf(lrelu(acc[i][j].x + bv.x)),
                        f2bf(lrelu(acc[i][j].y + bv.y)),
                        f2bf(lrelu(acc[i][j].z + bv.z)),
                        f2bf(lrelu(acc[i][j].w + bv.w)));
                    *(ushort4*)(dstp + (size_t)nn * 32) = pk;
                }
            }
        }
    } else {
#pragma unroll
        for (int i = 0; i < 4; ++i) {
            float4 bv = *(const float4*)(bias + co_l + i * 16);
            float s0 = 0.f, s1 = 0.f, s2 = 0.f, s3 = 0.f;
#pragma unroll
            for (int j = 0; j < 4; ++j) {
                int nn = nb0 + wn + j * 16 + l15;
                if (nn < NVAL) {
                    s0 += lrelu(acc[i][j].x + bv.x);
                    s1 += lrelu(acc[i][j].y + bv.y);
                    s2 += lrelu(acc[i][j].z + bv.z);
                    s3 += lrelu(acc[i][j].w + bv.w);
                }
            }
#pragma unroll
            for (int off = 1; off < 16; off <<= 1) {
                s0 += __shfl_xor(s0, off, 64);
                s1 += __shfl_xor(s1, off, 64);
                s2 += __shfl_xor(s2, off, 64);
                s3 += __shfl_xor(s3, off, 64);
            }
            if (l15 == 0) {
                float* pp = pool + b * 256 + co_l + i * 16;
                atomicAdd(pp + 0, s0); atomicAdd(pp + 1, s1);
                atomicAdd(pp + 2, s2); atomicAdd(pp + 3, s3);
            }
        }
    }
}

// kern[b][o] = (1/3600) * sum_c pool[b][c]*w3[o][c] + b3[o]
__global__ __launch_bounds__(256)
void kern_gemm_k(const float* __restrict__ p, const float* __restrict__ w3,
                 const float* __restrict__ b3, float* __restrict__ kern)
{
    const int b = blockIdx.y;
    const int o = blockIdx.x * 256 + threadIdx.x;
    __shared__ float pv[CCH];
    pv[threadIdx.x] = p[b * CCH + threadIdx.x] * (1.f / 3600.f);
    __syncthreads();
    float acc = b3[o];
    const float* wr = w3 + (size_t)o * CCH;
#pragma unroll 4
    for (int c = 0; c < CCH; c += 4) {
        float4 wv = *(const float4*)(wr + c);
        acc += wv.x * pv[c] + wv.y * pv[c + 1] + wv.z * pv[c + 2] + wv.w * pv[c + 3];
    }
    kern[(size_t)b * (9 * CCH) + o] = acc;
}

// Per-sample depthwise 3x3 SAME + bias, fp32, LDS-staged.
// One block (256 thr) per (b,c) plane. LDS tile 66 rows x 67 stride, zero halo;
// interior (y,x) at [(y+1)*67 + 1 + x]. Read pattern bank=(3y+4xq)%32 -> 2-way (free).
__global__ __launch_bounds__(256)
void dw_k(const float* __restrict__ x, const float* __restrict__ kern,
          const float* __restrict__ bias, float* __restrict__ out)
{
    __shared__ float t[66 * 67];
    const int tid = threadIdx.x;
    const int bc = blockIdx.x;
    const int c = bc & (CCH - 1);
    const int b = bc >> 8;

    // zero whole tile (halo included)
#pragma unroll
    for (int i = 0; i < 18; ++i) {
        int idx = tid + i * 256;
        if (idx < 66 * 67) t[idx] = 0.f;
    }

    const float* kp = kern + (size_t)b * (9 * CCH) + c * 9;
    float k[9];
#pragma unroll
    for (int q = 0; q < 9; ++q) k[q] = kp[q];
    const float bs = bias[c];
    const float* xp = x + (size_t)bc * 4096;
    float* op = out + (size_t)bc * 4096;
    __syncthreads();

    // stage plane: float4 global loads, scalar LDS writes (conflict-free: same row per wave)
#pragma unroll
    for (int i = 0; i < 4; ++i) {
        int p4 = tid + i * 256;            // float4 index 0..1023
        float4 v = *(const float4*)(xp + p4 * 4);
        int yy = p4 >> 4, xx = (p4 & 15) * 4;
        float* d = &t[(yy + 1) * 67 + 1 + xx];
        d[0] = v.x; d[1] = v.y; d[2] = v.z; d[3] = v.w;
    }
    __syncthreads();

#pragma unroll
    for (int i = 0; i < 4; ++i) {
        int p4 = tid + i * 256;
        int yy = p4 >> 4, xx = (p4 & 15) * 4;
        float r[3][6];
#pragma unroll
        for (int dy = 0; dy < 3; ++dy)
#pragma unroll
            for (int dx = 0; dx < 6; ++dx)
                r[dy][dx] = t[(yy + dy) * 67 + xx + dx];
        float4 o;
        float* ov = (float*)&o;
#pragma unroll
        for (int j = 0; j < 4; ++j) {
            float a = bs;
#pragma unroll
            for (int dy = 0; dy < 3; ++dy)
#pragma unroll
                for (int dx = 0; dx < 3; ++dx)
                    a += k[dy * 3 + dx] * r[dy][j + dx];
            ov[j] = a;
        }
        *(float4*)(op + p4 * 4) = o;
    }
}

extern "C" void kernel_launch(void* const* d_in, const int* in_sizes, int n_in,
                              void* d_out, int out_size, void* d_ws, size_t ws_size,
                              hipStream_t stream)
{
    const float* x    = (const float*)d_in[0];
    const float* kin  = (const float*)d_in[1];
    const float* w1   = (const float*)d_in[2];
    const float* b1   = (const float*)d_in[3];
    const float* w2   = (const float*)d_in[4];
    const float* b2   = (const float*)d_in[5];
    const float* w3   = (const float*)d_in[6];
    const float* b3   = (const float*)d_in[7];
    const float* bias = (const float*)d_in[8];

    // ws: imA [16][8][4096][32] bf16 | h1 [16][8][3844][32] bf16 (+slack) | w1t | w2t | pool | kern
    unsigned short* imA = (unsigned short*)d_ws;
    unsigned short* h1  = imA + (size_t)16 * 8 * 4096 * 32;
    unsigned short* w1t = h1 + (size_t)16 * 8 * 3844 * 32 + 8192;   // slack for clamped-tap reads
    unsigned short* w2t = w1t + (size_t)72 * 4 * 2048;
    float* pool = (float*)(w2t + (size_t)72 * 4 * 2048);
    float* kern = pool + 16 * 256;

    float* out = (float*)d_out;

    hipLaunchKernelGGL(zero_pool_k, dim3(16), dim3(256), 0, stream, pool);
    hipLaunchKernelGGL(nhwc_k, dim3(8, 64, 16), dim3(256), 0, stream, kin, imA);
    hipLaunchKernelGGL(wtr_k, dim3(72, 2), dim3(256), 0, stream, w1, w2, w1t, w2t);
    hipLaunchKernelGGL((convmm_k<0, 64, 62>), dim3(2, 31, 16), dim3(256), 0, stream,
                       imA, w1t, b1, h1, (float*)nullptr);
    hipLaunchKernelGGL((convmm_k<1, 62, 60>), dim3(2, 29, 16), dim3(256), 0, stream,
                       h1, w2t, b2, (unsigned short*)nullptr, pool);
    hipLaunchKernelGGL(kern_gemm_k, dim3(9, 16), dim3(256), 0, stream, pool, w3, b3, kern);
    hipLaunchKernelGGL(dw_k, dim3(16 * 256), dim3(256), 0, stream, x, kern, bias, out);
}

// Round 5
// 351.897 us; speedup vs baseline: 7.4257x; 1.2417x over previous
//
#include <hip/hip_runtime.h>
#include <hip/hip_bf16.h>
#include <stdint.h>

#define CCH 256

typedef __attribute__((ext_vector_type(8))) short short8;
typedef __attribute__((ext_vector_type(4))) float f32x4;

__device__ __forceinline__ float lrelu(float v) { return v > 0.f ? v : 0.1f * v; }

__device__ __forceinline__ unsigned short f2bf(float f) {
    __hip_bfloat16 h = __float2bfloat16(f);
    return *reinterpret_cast<unsigned short*>(&h);
}

// async global->LDS, 16B per lane; global addr per-lane, LDS dst wave-uniform (+lane*16)
__device__ __forceinline__ void gl_lds16(const void* g, void* s) {
    __builtin_amdgcn_global_load_lds(
        (const __attribute__((address_space(1))) unsigned int*)(uintptr_t)g,
        (__attribute__((address_space(3))) unsigned int*)(unsigned int)(uintptr_t)s,
        16, 0, 0);
}

// NCHW fp32 -> channel-chunked bf16: out[b][kc][y*64+x][32ci].
// grid (8 kc, 64 y, 16 b), block 256.
__global__ __launch_bounds__(256)
void nhwc_k(const float* __restrict__ in, unsigned short* __restrict__ out)
{
    __shared__ float t[32][65];
    const int tid = threadIdx.x;
    const int kc = blockIdx.x, y = blockIdx.y, b = blockIdx.z;
    const float* src = in + ((size_t)(b * 256 + kc * 32)) * 4096 + y * 64;
#pragma unroll
    for (int i = 0; i < 2; ++i) {
        int idx = tid + i * 256;            // 0..511
        int cl = idx >> 4, xg = idx & 15;
        float4 v = *(const float4*)(src + (size_t)cl * 4096 + xg * 4);
        t[cl][xg * 4 + 0] = v.x; t[cl][xg * 4 + 1] = v.y;
        t[cl][xg * 4 + 2] = v.z; t[cl][xg * 4 + 3] = v.w;
    }
    __syncthreads();
    const int x = tid >> 2, cg = tid & 3;
    union { unsigned short us[8]; uint4 v; } u;
#pragma unroll
    for (int j = 0; j < 8; ++j) u.us[j] = f2bf(t[cg * 8 + j][x]);
    unsigned short* dst = out + (((size_t)(b * 8 + kc) * 4096 + y * 64 + x) * 32 + cg * 8);
    *(uint4*)dst = u.v;
}

// w[co][ci][9] fp32 -> wt[kc][t][q][co][8] bf16 (ci = kc*32 + q*8 + u).
// grid (72, 2), block 256 (= co).
__global__ __launch_bounds__(256)
void wtr_k(const float* __restrict__ w1, const float* __restrict__ w2,
           unsigned short* __restrict__ o1, unsigned short* __restrict__ o2)
{
    const int kc = blockIdx.x / 9, t = blockIdx.x - kc * 9;
    const float* w = blockIdx.y ? w2 : w1;
    unsigned short* o = blockIdx.y ? o2 : o1;
    const int co = threadIdx.x;
#pragma unroll
    for (int q = 0; q < 4; ++q) {
        union { unsigned short us[8]; uint4 v; } u;
#pragma unroll
        for (int uu = 0; uu < 8; ++uu)
            u.us[uu] = f2bf(w[((size_t)co * 256 + kc * 32 + q * 8 + uu) * 9 + t]);
        *(uint4*)(o + ((size_t)((kc * 9 + t) * 4 + q)) * 2048 + co * 8) = u.v;
    }
}

__global__ __launch_bounds__(256)
void zero_pool_k(float* __restrict__ p) { p[blockIdx.x * 256 + threadIdx.x] = 0.f; }

// Implicit-GEMM 3x3 VALID conv, bf16 MFMA 16x16x32.
// M=Cout=256 (full, single m-tile), N=pixels (block 128), K = 72 stages (kc,tap) x 32,
// 2 stages per barrier. Wave tile 128(m) x 64(n): a[8] x b[4] frags, acc 8x4.
// im: [b][kc][WIN*WIN][32] bf16; wt: [kc][t][q][co=256][8] bf16.
// POOL=0: h1 out [b][kc'][NVAL][32] (bias+lrelu, bf16). POOL=1: sum -> atomicAdd pool.
// grid (ceil(NVAL/128), 16 b), block 256, 2 blocks/CU.
template<int POOL, int WIN, int WOUT>
__global__ __launch_bounds__(256, 2)
void convmm_k(const unsigned short* __restrict__ im, const unsigned short* __restrict__ wt,
              const float* __restrict__ bias, unsigned short* __restrict__ outp,
              float* __restrict__ pool)
{
    constexpr int HINPIX = WIN * WIN;
    constexpr int NVAL   = WOUT * WOUT;
    // Per pair-slot u: A = 4 q-planes [256 co][8], plane stride 2056 shorts (+16B pad);
    //                  B = 4 q-planes [128 px][8], plane stride 1032 shorts (+16B pad).
    // Au at u*12352, Bu at 2*12352 + u*... -> pack: [A0 A1 B0 B1]
    __shared__ __align__(16) short Ls[2 * 4 * 2056 + 2 * 4 * 1032];

    const int tid  = threadIdx.x;
    const int wave = tid >> 6;
    const int lane = tid & 63;
    const int quad = lane >> 4;
    const int l15  = lane & 15;
    const int wm   = (wave & 1) * 128;     // m offset of wave tile (co)
    const int wn   = (wave >> 1) * 64;     // n offset of wave tile (px)
    const int nb0  = blockIdx.x * 128;
    const int b    = blockIdx.y;

    short* const Aq = Ls;                   // A planes: u*4*2056
    short* const Bq = Ls + 2 * 4 * 2056;    // B planes: u*4*1032

    // A staging: wave stages plane q=wave; 4 calls h, rows h*64+lane (8 shorts each)
    const unsigned short* abase = wt + (size_t)wave * 2048 + (size_t)lane * 8;
    // B staging: wave stages plane q=wave; 2 calls h, px rows h*64+lane
    size_t bofs[2];
#pragma unroll
    for (int h = 0; h < 2; ++h) {
        int nn = nb0 + h * 64 + lane;
        if (nn > NVAL - 1) nn = NVAL - 1;
        int y = nn / WOUT, x = nn - y * WOUT;
        bofs[h] = ((size_t)(b * 8) * HINPIX + (size_t)y * WIN + x) * 32 + wave * 8;
    }

    f32x4 acc[8][4];
#pragma unroll
    for (int i = 0; i < 8; ++i)
#pragma unroll
        for (int j = 0; j < 4; ++j) { f32x4 z = {0.f, 0.f, 0.f, 0.f}; acc[i][j] = z; }

    for (int s = 0; s < 72; s += 2) {
#pragma unroll
        for (int u = 0; u < 2; ++u) {
            const int ss = s + u;
            const int kc = ss / 9, t = ss - kc * 9;
            const int ky = t / 3, kx = t - ky * 3;
            const size_t aoff = (size_t)ss * 8192;
            const size_t boff = ((size_t)kc * HINPIX + ky * WIN + kx) * 32;
            short* al = Aq + (u * 4 + wave) * 2056;
            short* bl = Bq + (u * 4 + wave) * 1032;
#pragma unroll
            for (int h = 0; h < 4; ++h)
                gl_lds16(abase + aoff + h * 512, al + h * 512);
#pragma unroll
            for (int h = 0; h < 2; ++h)
                gl_lds16(im + bofs[h] + boff, bl + h * 512);
        }
        __syncthreads();
#pragma unroll
        for (int u = 0; u < 2; ++u) {
            const short* ap = Aq + (u * 4 + quad) * 2056;
            const short* bp = Bq + (u * 4 + quad) * 1032;
            short8 a[8], bf[4];
#pragma unroll
            for (int i = 0; i < 8; ++i)
                a[i]  = *(const short8*)(ap + (wm + i * 16 + l15) * 8);
#pragma unroll
            for (int j = 0; j < 4; ++j)
                bf[j] = *(const short8*)(bp + (wn + j * 16 + l15) * 8);
#pragma unroll
            for (int i = 0; i < 8; ++i)
#pragma unroll
                for (int j = 0; j < 4; ++j)
                    acc[i][j] = __builtin_amdgcn_mfma_f32_16x16x32_bf16(a[i], bf[j], acc[i][j], 0, 0, 0);
        }
        __syncthreads();
    }

    // D layout: col(px)=l15, row(co)=quad*4+reg
    const int co_l = wm + quad * 4;
    if (!POOL) {
#pragma unroll
        for (int i = 0; i < 8; ++i) {
            const int c0 = co_l + i * 16;
            float4 bv = *(const float4*)(bias + c0);
            unsigned short* dstp = outp + ((size_t)(b * 8 + (c0 >> 5)) * NVAL) * 32 + (c0 & 31);
#pragma unroll
            for (int j = 0; j < 4; ++j) {
                int nn = nb0 + wn + j * 16 + l15;
                if (nn < NVAL) {
                    ushort4 pk = make_ushort4(
                        f2bf(lrelu(acc[i][j].x + bv.x)),
                        f2bf(lrelu(acc[i][j].y + bv.y)),
                        f2bf(lrelu(acc[i][j].z + bv.z)),
                        f2bf(lrelu(acc[i][j].w + bv.w)));
                    *(ushort4*)(dstp + (size_t)nn * 32) = pk;
                }
            }
        }
    } else {
#pragma unroll
        for (int i = 0; i < 8; ++i) {
            const int c0 = co_l + i * 16;
            float4 bv = *(const float4*)(bias + c0);
            float s0 = 0.f, s1 = 0.f, s2 = 0.f, s3 = 0.f;
#pragma unroll
            for (int j = 0; j < 4; ++j) {
                int nn = nb0 + wn + j * 16 + l15;
                if (nn < NVAL) {
                    s0 += lrelu(acc[i][j].x + bv.x);
                    s1 += lrelu(acc[i][j].y + bv.y);
                    s2 += lrelu(acc[i][j].z + bv.z);
                    s3 += lrelu(acc[i][j].w + bv.w);
                }
            }
#pragma unroll
            for (int off = 1; off < 16; off <<= 1) {
                s0 += __shfl_xor(s0, off, 64);
                s1 += __shfl_xor(s1, off, 64);
                s2 += __shfl_xor(s2, off, 64);
                s3 += __shfl_xor(s3, off, 64);
            }
            if (l15 == 0) {
                float* pp = pool + b * 256 + c0;
                atomicAdd(pp + 0, s0); atomicAdd(pp + 1, s1);
                atomicAdd(pp + 2, s2); atomicAdd(pp + 3, s3);
            }
        }
    }
}

// kern[b][o] = (1/3600) * sum_c pool[b][c]*w3[o][c] + b3[o]
__global__ __launch_bounds__(256)
void kern_gemm_k(const float* __restrict__ p, const float* __restrict__ w3,
                 const float* __restrict__ b3, float* __restrict__ kern)
{
    const int b = blockIdx.y;
    const int o = blockIdx.x * 256 + threadIdx.x;
    __shared__ float pv[CCH];
    pv[threadIdx.x] = p[b * CCH + threadIdx.x] * (1.f / 3600.f);
    __syncthreads();
    float acc = b3[o];
    const float* wr = w3 + (size_t)o * CCH;
#pragma unroll 4
    for (int c = 0; c < CCH; c += 4) {
        float4 wv = *(const float4*)(wr + c);
        acc += wv.x * pv[c] + wv.y * pv[c + 1] + wv.z * pv[c + 2] + wv.w * pv[c + 3];
    }
    kern[(size_t)b * (9 * CCH) + o] = acc;
}

// Per-sample depthwise 3x3 SAME + bias, fp32, LDS-staged.
// One block (256 thr) per (b,c) plane. LDS tile 66 rows x 67 stride, zero halo.
__global__ __launch_bounds__(256)
void dw_k(const float* __restrict__ x, const float* __restrict__ kern,
          const float* __restrict__ bias, float* __restrict__ out)
{
    __shared__ float t[66 * 67];
    const int tid = threadIdx.x;
    const int bc = blockIdx.x;
    const int c = bc & (CCH - 1);
    const int b = bc >> 8;

#pragma unroll
    for (int i = 0; i < 18; ++i) {
        int idx = tid + i * 256;
        if (idx < 66 * 67) t[idx] = 0.f;
    }

    const float* kp = kern + (size_t)b * (9 * CCH) + c * 9;
    float k[9];
#pragma unroll
    for (int q = 0; q < 9; ++q) k[q] = kp[q];
    const float bs = bias[c];
    const float* xp = x + (size_t)bc * 4096;
    float* op = out + (size_t)bc * 4096;
    __syncthreads();

#pragma unroll
    for (int i = 0; i < 4; ++i) {
        int p4 = tid + i * 256;            // float4 index 0..1023
        float4 v = *(const float4*)(xp + p4 * 4);
        int yy = p4 >> 4, xx = (p4 & 15) * 4;
        float* d = &t[(yy + 1) * 67 + 1 + xx];
        d[0] = v.x; d[1] = v.y; d[2] = v.z; d[3] = v.w;
    }
    __syncthreads();

#pragma unroll
    for (int i = 0; i < 4; ++i) {
        int p4 = tid + i * 256;
        int yy = p4 >> 4, xx = (p4 & 15) * 4;
        float r[3][6];
#pragma unroll
        for (int dy = 0; dy < 3; ++dy)
#pragma unroll
            for (int dx = 0; dx < 6; ++dx)
                r[dy][dx] = t[(yy + dy) * 67 + xx + dx];
        float4 o;
        float* ov = (float*)&o;
#pragma unroll
        for (int j = 0; j < 4; ++j) {
            float a = bs;
#pragma unroll
            for (int dy = 0; dy < 3; ++dy)
#pragma unroll
                for (int dx = 0; dx < 3; ++dx)
                    a += k[dy * 3 + dx] * r[dy][j + dx];
            ov[j] = a;
        }
        *(float4*)(op + p4 * 4) = o;
    }
}

extern "C" void kernel_launch(void* const* d_in, const int* in_sizes, int n_in,
                              void* d_out, int out_size, void* d_ws, size_t ws_size,
                              hipStream_t stream)
{
    const float* x    = (const float*)d_in[0];
    const float* kin  = (const float*)d_in[1];
    const float* w1   = (const float*)d_in[2];
    const float* b1   = (const float*)d_in[3];
    const float* w2   = (const float*)d_in[4];
    const float* b2   = (const float*)d_in[5];
    const float* w3   = (const float*)d_in[6];
    const float* b3   = (const float*)d_in[7];
    const float* bias = (const float*)d_in[8];

    // ws: imA [16][8][4096][32] bf16 | h1 [16][8][3844][32] bf16 (+slack) | w1t | w2t | pool | kern
    unsigned short* imA = (unsigned short*)d_ws;
    unsigned short* h1  = imA + (size_t)16 * 8 * 4096 * 32;
    unsigned short* w1t = h1 + (size_t)16 * 8 * 3844 * 32 + 8192;   // slack for clamped-tap reads
    unsigned short* w2t = w1t + (size_t)72 * 4 * 2048;
    float* pool = (float*)(w2t + (size_t)72 * 4 * 2048);
    float* kern = pool + 16 * 256;

    float* out = (float*)d_out;

    hipLaunchKernelGGL(zero_pool_k, dim3(16), dim3(256), 0, stream, pool);
    hipLaunchKernelGGL(nhwc_k, dim3(8, 64, 16), dim3(256), 0, stream, kin, imA);
    hipLaunchKernelGGL(wtr_k, dim3(72, 2), dim3(256), 0, stream, w1, w2, w1t, w2t);
    hipLaunchKernelGGL((convmm_k<0, 64, 62>), dim3(31, 16), dim3(256), 0, stream,
                       imA, w1t, b1, h1, (float*)nullptr);
    hipLaunchKernelGGL((convmm_k<1, 62, 60>), dim3(29, 16), dim3(256), 0, stream,
                       h1, w2t, b2, (unsigned short*)nullptr, pool);
    hipLaunchKernelGGL(kern_gemm_k, dim3(9, 16), dim3(256), 0, stream, pool, w3, b3, kern);
    hipLaunchKernelGGL(dw_k, dim3(16 * 256), dim3(256), 0, stream, x, kern, bias, out);
}